// Round 2
// baseline (1041.567 us; speedup 1.0000x reference)
//
#include <hip/hip_runtime.h>

// MADE flow: u = (x - m)*exp(-a), logdet = -sum(a)
// B=524288, NI=32, H=128, NC=64.
// R4: persistent-stream structure. All 72 weight frags (72KB) + biases staged
// in LDS ONCE per block; each wave then streams 4 row-tiles of 16 rows with
// double-buffered x/cond prefetch (issue next tile's loads before computing
// current tile) -> continuous HBM traffic, no per-iter barriers, no spill.
// nt=1 keeps peak regs ~112 (<128 => 4 waves/SIMD, 2 blocks/CU by LDS).

#define B_ROWS 524288
#define NI 32
#define HD 128
#define NC 64
#define ITERS 4

// K=32 fragments: 1 frag = 16(j) x 32(k) f16 = 512 halfs = 1KB
#define L2_BASE 24    // L1 frags: 8 jt * 3 kt = 24
#define L3_BASE 56    // L2 frags: 8 jt * 4 kt = 32
#define N_FRAGS 72    // L3 frags: 4 jt * 4 kt = 16

typedef _Float16 half8 __attribute__((ext_vector_type(8)));
typedef float f32x4 __attribute__((ext_vector_type(4)));

__device__ inline f32x4 relu4(f32x4 v) {
  v[0] = fmaxf(v[0], 0.f); v[1] = fmaxf(v[1], 0.f);
  v[2] = fmaxf(v[2], 0.f); v[3] = fmaxf(v[3], 0.f);
  return v;
}

__device__ inline half8 cvt8(f32x4 lo, f32x4 hi) {
  half8 h;
  h[0] = (_Float16)lo[0]; h[1] = (_Float16)lo[1];
  h[2] = (_Float16)lo[2]; h[3] = (_Float16)lo[3];
  h[4] = (_Float16)hi[0]; h[5] = (_Float16)hi[1];
  h[6] = (_Float16)hi[2]; h[7] = (_Float16)hi[3];
  return h;
}

// ---------------- prep: masked f16 weights in K=32 MFMA-A fragment order ----
// Fragment (frag, lane) holds A[m][k]: m = jt*16 + (lane&15),
// k = kt*32 + (e>>2)*16 + (lane>>4)*4 + (e&3)  (e=0..7, two stacked K=16
// halves). Stored at wf[frag*512 + lane*8 + e].
__global__ void prep_weights(const float* __restrict__ W1, const float* __restrict__ Wc,
                             const float* __restrict__ W2, const float* __restrict__ W3,
                             _Float16* __restrict__ wf) {
  int tid = blockIdx.x * blockDim.x + threadIdx.x;
  if (tid >= N_FRAGS * 64) return;
  int frag = tid >> 6;
  int lane = tid & 63;
  int q = lane >> 4, c = lane & 15;
  int L, jt, kt;
  if (frag < L2_BASE)      { L = 0; jt = frag / 3;              kt = frag % 3; }
  else if (frag < L3_BASE) { L = 1; jt = (frag - L2_BASE) >> 2; kt = (frag - L2_BASE) & 3; }
  else                     { L = 2; jt = (frag - L3_BASE) >> 2; kt = (frag - L3_BASE) & 3; }
  int j = jt * 16 + c;  // output unit (row of W)
  half8 v;
#pragma unroll
  for (int e = 0; e < 8; ++e) {
    int k = kt * 32 + (e >> 2) * 16 + q * 4 + (e & 3);
    float w;
    if (L == 0) {
      // layer1 K-dim is [x(32) | cond(64)]; mask m1 = (j%31 >= k), Wc unmasked
      if (k < NI) w = ((j % 31) >= k) ? W1[j * NI + k] : 0.f;
      else        w = Wc[j * NC + (k - NI)];
    } else if (L == 1) {
      w = ((j % 31) >= (k % 31)) ? W2[j * HD + k] : 0.f;          // m2
    } else {
      w = (((j % 32) - 1) >= (k % 31)) ? W3[j * HD + k] : 0.f;    // m3
    }
    v[e] = (_Float16)w;
  }
  *(half8*)(wf + (size_t)tid * 8) = v;
}

// ---------------- fused main kernel ----------------
// 8 waves/block, each wave streams ITERS=4 tiles of 16 rows.
// Grid = B/(8*16*ITERS) = 1024 blocks.

// One row-tile: cvt raw->f16 frags, prefetch next tile's raw loads,
// L1/L2/L3 MFMA (all weights from LDS), fused epilogue.
#define BODY(RX, RC, NRX, NRC, IT)                                            \
  {                                                                           \
    half8 bf0 = cvt8(RX[0], RX[1]);                                           \
    half8 bf1 = cvt8(RC[0], RC[1]);                                           \
    half8 bf2 = cvt8(RC[2], RC[3]);                                           \
    if ((IT) < ITERS - 1) { /* prefetch next tile: hidden under compute */    \
      long nr = blockBase + ((IT) + 1) * 128 + wid * 16 + c;                  \
      const f32x4* xr = (const f32x4*)(x + nr * NI);                          \
      const f32x4* cr = (const f32x4*)(cond + nr * NC);                       \
      NRX[0] = xr[q];     NRX[1] = xr[4 + q];                                 \
      NRC[0] = cr[q];     NRC[1] = cr[4 + q];                                 \
      NRC[2] = cr[8 + q]; NRC[3] = cr[12 + q];                                \
    }                                                                         \
    f32x4 acc[4]; half8 h1[4], h2[4];                                         \
    /* ---- layer 1: 8 jt x 3 kt32, jh-split keeps acc file at 16 regs */     \
    _Pragma("unroll")                                                         \
    for (int jh = 0; jh < 2; ++jh) {                                          \
      _Pragma("unroll")                                                       \
      for (int j4 = 0; j4 < 4; ++j4)                                          \
        acc[j4] = *(const f32x4*)(blds + (jh * 4 + j4) * 16 + q * 4);         \
      _Pragma("unroll")                                                       \
      for (int j4 = 0; j4 < 4; ++j4) {                                        \
        int jt = jh * 4 + j4;                                                 \
        _Pragma("unroll")                                                     \
        for (int kt = 0; kt < 3; ++kt) {                                      \
          half8 a = *(const half8*)(wlds + (((jt * 3 + kt) * 64 + lane) << 3)); \
          half8 bb = (kt == 0) ? bf0 : ((kt == 1) ? bf1 : bf2);               \
          acc[j4] = __builtin_amdgcn_mfma_f32_16x16x32_f16(a, bb, acc[j4], 0, 0, 0); \
        }                                                                     \
      }                                                                       \
      _Pragma("unroll")                                                       \
      for (int p = 0; p < 2; ++p)                                             \
        h1[jh * 2 + p] = cvt8(relu4(acc[p * 2]), relu4(acc[p * 2 + 1]));      \
    }                                                                         \
    /* ---- layer 2: 8 jt x 4 kt32 */                                         \
    _Pragma("unroll")                                                         \
    for (int jh = 0; jh < 2; ++jh) {                                          \
      _Pragma("unroll")                                                       \
      for (int j4 = 0; j4 < 4; ++j4)                                          \
        acc[j4] = *(const f32x4*)(blds + 128 + (jh * 4 + j4) * 16 + q * 4);   \
      _Pragma("unroll")                                                       \
      for (int j4 = 0; j4 < 4; ++j4) {                                        \
        int jt = jh * 4 + j4;                                                 \
        _Pragma("unroll")                                                     \
        for (int kt = 0; kt < 4; ++kt) {                                      \
          half8 a = *(const half8*)(wlds + (((L2_BASE + jt * 4 + kt) * 64 + lane) << 3)); \
          acc[j4] = __builtin_amdgcn_mfma_f32_16x16x32_f16(a, h1[kt], acc[j4], 0, 0, 0); \
        }                                                                     \
      }                                                                       \
      _Pragma("unroll")                                                       \
      for (int p = 0; p < 2; ++p)                                             \
        h2[jh * 2 + p] = cvt8(relu4(acc[p * 2]), relu4(acc[p * 2 + 1]));      \
    }                                                                         \
    /* ---- layer 3: 4 jt x 4 kt32 -> acc[0..1]=m_, acc[2..3]=a */            \
    _Pragma("unroll")                                                         \
    for (int jt = 0; jt < 4; ++jt)                                            \
      acc[jt] = *(const f32x4*)(blds + 256 + jt * 16 + q * 4);                \
    _Pragma("unroll")                                                         \
    for (int jt = 0; jt < 4; ++jt) {                                          \
      _Pragma("unroll")                                                       \
      for (int kt = 0; kt < 4; ++kt) {                                        \
        half8 a = *(const half8*)(wlds + (((L3_BASE + jt * 4 + kt) * 64 + lane) << 3)); \
        acc[jt] = __builtin_amdgcn_mfma_f32_16x16x32_f16(a, h2[kt], acc[jt], 0, 0, 0); \
      }                                                                       \
    }                                                                         \
    /* ---- epilogue: lane owns row m; x still live in RX */                  \
    {                                                                         \
      long m = blockBase + (IT) * 128 + wid * 16 + c;                         \
      f32x4 xa = RX[0], xb = RX[1];                                           \
      f32x4 ua, ub;                                                           \
      float s = 0.f;                                                          \
      _Pragma("unroll")                                                       \
      for (int i = 0; i < 4; ++i) {                                           \
        float aa = fminf(fmaxf(acc[2][i], -5.f), 5.f);                        \
        float ab = fminf(fmaxf(acc[3][i], -5.f), 5.f);                        \
        ua[i] = (xa[i] - acc[0][i]) * __expf(-aa);                            \
        ub[i] = (xb[i] - acc[1][i]) * __expf(-ab);                            \
        s += aa + ab;                                                         \
      }                                                                       \
      *(f32x4*)(out + m * NI + q * 4) = ua;                                   \
      *(f32x4*)(out + m * NI + 16 + q * 4) = ub;                              \
      s += __shfl_xor(s, 16);                                                 \
      s += __shfl_xor(s, 32);                                                 \
      if (q == 0) out[(long)B_ROWS * NI + m] = -s;                            \
    }                                                                         \
  }

__global__ __launch_bounds__(512, 4) void made_fused(
    const float* __restrict__ x, const float* __restrict__ cond,
    const float* __restrict__ b1, const float* __restrict__ b2,
    const float* __restrict__ b3, const _Float16* __restrict__ wf,
    float* __restrict__ out) {
  // ALL weight fragments staged in LDS: 72 * 1KB = 72KB; biases 1.25KB.
  __shared__ __align__(16) _Float16 wlds[N_FRAGS * 512];
  __shared__ float blds[320];

  const int tid  = threadIdx.x;
  const int lane = tid & 63;
  const int wid  = tid >> 6;
  const int q = lane >> 4, c = lane & 15;
  const long blockBase = (long)blockIdx.x * (ITERS * 128);  // 512 rows/block

  // ---- one-time stage: 72KB weights via global_load_lds (9KB per wave) ----
  {
    const char* gsrc = (const char*)wf + wid * 9216;
    char* ldst = (char*)wlds + wid * 9216;
#pragma unroll
    for (int i = 0; i < 9; ++i) {
      __builtin_amdgcn_global_load_lds(
          (const __attribute__((address_space(1))) void*)(gsrc + i * 1024 + lane * 16),
          (__attribute__((address_space(3))) void*)(ldst + i * 1024),
          16, 0, 0);
    }
  }
  if (tid < 128)      blds[tid] = b1[tid];
  else if (tid < 256) blds[tid] = b2[tid - 128];
  else if (tid < 320) blds[tid] = b3[tid - 256];

  // ---- preload tile 0 activations (overlaps the LDS stage) ----
  f32x4 rxA[2], rcA[4], rxB[2], rcB[4];
  {
    long r = blockBase + wid * 16 + c;
    const f32x4* xr = (const f32x4*)(x + r * NI);
    const f32x4* cr = (const f32x4*)(cond + r * NC);
    rxA[0] = xr[q];     rxA[1] = xr[4 + q];
    rcA[0] = cr[q];     rcA[1] = cr[4 + q];
    rcA[2] = cr[8 + q]; rcA[3] = cr[12 + q];
  }

  __syncthreads();  // drains global_load_lds + bias writes; only barrier

  // ---- stream ITERS tiles, ping-pong raw buffers (static indices only) ----
#pragma unroll 1
  for (int ii = 0; ii < ITERS; ii += 2) {
    BODY(rxA, rcA, rxB, rcB, ii);
    BODY(rxB, rcB, rxA, rcA, ii + 1);
  }
}

extern "C" void kernel_launch(void* const* d_in, const int* in_sizes, int n_in,
                              void* d_out, int out_size, void* d_ws, size_t ws_size,
                              hipStream_t stream) {
  const float* x    = (const float*)d_in[0];
  const float* cond = (const float*)d_in[1];
  const float* W1   = (const float*)d_in[2];
  const float* b1   = (const float*)d_in[3];
  const float* Wc   = (const float*)d_in[4];
  const float* W2   = (const float*)d_in[5];
  const float* b2   = (const float*)d_in[6];
  const float* W3   = (const float*)d_in[7];
  const float* b3   = (const float*)d_in[8];
  _Float16* wf = (_Float16*)d_ws;  // 72 frags * 512 halfs * 2B = 72 KB

  prep_weights<<<(N_FRAGS * 64 + 255) / 256, 256, 0, stream>>>(W1, Wc, W2, W3, wf);
  made_fused<<<B_ROWS / (ITERS * 128), 512, 0, stream>>>(x, cond, b1, b2, b3, wf, (float*)d_out);
}

// Round 3
// 313.458 us; speedup vs baseline: 3.3228x; 3.3228x over previous
//
#include <hip/hip_runtime.h>

// MADE flow: u = (x - m)*exp(-a), logdet = -sum(a)
// B=524288, NI=32, H=128, NC=64.
// R5: persistent streaming like R4 but STRAIGHT-LINE (ITERS=4 fully unrolled,
// static iteration index, no loop-carried ping-pong across a back-edge).
// R4's 10x scratch traffic (FETCH 1.5GB/WRITE 0.9GB) was regalloc failure on
// the unroll-1 loop; R1's straight-line code allocated fine, so we keep the
// DAG shape. L2/L3 weights in 48KB LDS (barrier in body 0 only), L1 weights
// from global (L2-resident). Tile-0 reg loads issued BEFORE the LDS stage so
// body-0 cvt doesn't wait (vmcnt is in-order) on the 48KB stage.

#define B_ROWS 524288
#define NI 32
#define HD 128
#define NC 64
#define ITERS 4

// K=32 fragments: 1 frag = 16(j) x 32(k) f16 = 512 halfs = 1KB
#define L2_BASE 24    // L1 frags: 8 jt * 3 kt = 24
#define L3_BASE 56    // L2 frags: 8 jt * 4 kt = 32
#define N_FRAGS 72    // L3 frags: 4 jt * 4 kt = 16

typedef _Float16 half8 __attribute__((ext_vector_type(8)));
typedef float f32x4 __attribute__((ext_vector_type(4)));

__device__ inline f32x4 relu4(f32x4 v) {
  v[0] = fmaxf(v[0], 0.f); v[1] = fmaxf(v[1], 0.f);
  v[2] = fmaxf(v[2], 0.f); v[3] = fmaxf(v[3], 0.f);
  return v;
}

__device__ inline half8 cvt8(f32x4 lo, f32x4 hi) {
  half8 h;
  h[0] = (_Float16)lo[0]; h[1] = (_Float16)lo[1];
  h[2] = (_Float16)lo[2]; h[3] = (_Float16)lo[3];
  h[4] = (_Float16)hi[0]; h[5] = (_Float16)hi[1];
  h[6] = (_Float16)hi[2]; h[7] = (_Float16)hi[3];
  return h;
}

// ---------------- prep: masked f16 weights in K=32 MFMA-A fragment order ----
// Fragment (frag, lane) holds A[m][k]: m = jt*16 + (lane&15),
// k = kt*32 + (e>>2)*16 + (lane>>4)*4 + (e&3)  (e=0..7, two stacked K=16
// halves). Stored at wf[frag*512 + lane*8 + e].
__global__ void prep_weights(const float* __restrict__ W1, const float* __restrict__ Wc,
                             const float* __restrict__ W2, const float* __restrict__ W3,
                             _Float16* __restrict__ wf) {
  int tid = blockIdx.x * blockDim.x + threadIdx.x;
  if (tid >= N_FRAGS * 64) return;
  int frag = tid >> 6;
  int lane = tid & 63;
  int q = lane >> 4, c = lane & 15;
  int L, jt, kt;
  if (frag < L2_BASE)      { L = 0; jt = frag / 3;              kt = frag % 3; }
  else if (frag < L3_BASE) { L = 1; jt = (frag - L2_BASE) >> 2; kt = (frag - L2_BASE) & 3; }
  else                     { L = 2; jt = (frag - L3_BASE) >> 2; kt = (frag - L3_BASE) & 3; }
  int j = jt * 16 + c;  // output unit (row of W)
  half8 v;
#pragma unroll
  for (int e = 0; e < 8; ++e) {
    int k = kt * 32 + (e >> 2) * 16 + q * 4 + (e & 3);
    float w;
    if (L == 0) {
      // layer1 K-dim is [x(32) | cond(64)]; mask m1 = (j%31 >= k), Wc unmasked
      if (k < NI) w = ((j % 31) >= k) ? W1[j * NI + k] : 0.f;
      else        w = Wc[j * NC + (k - NI)];
    } else if (L == 1) {
      w = ((j % 31) >= (k % 31)) ? W2[j * HD + k] : 0.f;          // m2
    } else {
      w = (((j % 32) - 1) >= (k % 31)) ? W3[j * HD + k] : 0.f;    // m3
    }
    v[e] = (_Float16)w;
  }
  *(half8*)(wf + (size_t)tid * 8) = v;
}

// ---------------- fused main kernel ----------------
// 8 waves/block; each wave streams ITERS=4 tiles of 16 rows, straight-line.
// Grid = B/(8*16*ITERS) = 1024 blocks.

// One row-tile: cvt raw->f16 frags, (statically) prefetch next tile's raw
// loads, L1 (global weights) / L2 / L3 (LDS weights), fused epilogue.
// SYNC=1 inserts the one __syncthreads between L1 and L2 (body 0 only).
#define BODY(RX, RC, NRX, NRC, IT, SYNC)                                      \
  {                                                                           \
    half8 bf0 = cvt8(RX[0], RX[1]);                                           \
    half8 bf1 = cvt8(RC[0], RC[1]);                                           \
    half8 bf2 = cvt8(RC[2], RC[3]);                                           \
    if ((IT) < ITERS - 1) { /* static: prefetch next tile under compute */    \
      long nr = blockBase + ((IT) + 1) * 128 + wid * 16 + c;                  \
      const f32x4* xr = (const f32x4*)(x + nr * NI);                          \
      const f32x4* cr = (const f32x4*)(cond + nr * NC);                       \
      NRX[0] = xr[q];     NRX[1] = xr[4 + q];                                 \
      NRC[0] = cr[q];     NRC[1] = cr[4 + q];                                 \
      NRC[2] = cr[8 + q]; NRC[3] = cr[12 + q];                                \
    }                                                                         \
    f32x4 acc[4]; half8 h1[4], h2[4];                                         \
    /* ---- layer 1: 8 jt x 3 kt32, weights from GLOBAL (L2-resident) */      \
    _Pragma("unroll")                                                         \
    for (int jh = 0; jh < 2; ++jh) {                                          \
      _Pragma("unroll")                                                       \
      for (int j4 = 0; j4 < 4; ++j4)                                          \
        acc[j4] = *(const f32x4*)(b1 + (jh * 4 + j4) * 16 + q * 4);           \
      _Pragma("unroll")                                                       \
      for (int j4 = 0; j4 < 4; ++j4) {                                        \
        int jt = jh * 4 + j4;                                                 \
        _Pragma("unroll")                                                     \
        for (int kt = 0; kt < 3; ++kt) {                                      \
          half8 a = *(const half8*)(wf + (((jt * 3 + kt) * 64 + lane) << 3)); \
          half8 bb = (kt == 0) ? bf0 : ((kt == 1) ? bf1 : bf2);               \
          acc[j4] = __builtin_amdgcn_mfma_f32_16x16x32_f16(a, bb, acc[j4], 0, 0, 0); \
        }                                                                     \
      }                                                                       \
      _Pragma("unroll")                                                       \
      for (int p = 0; p < 2; ++p)                                             \
        h1[jh * 2 + p] = cvt8(relu4(acc[p * 2]), relu4(acc[p * 2 + 1]));      \
    }                                                                         \
    if (SYNC) __syncthreads(); /* LDS weights ready (body 0 only) */          \
    /* ---- layer 2: 8 jt x 4 kt32, weights from LDS */                       \
    _Pragma("unroll")                                                         \
    for (int jh = 0; jh < 2; ++jh) {                                          \
      _Pragma("unroll")                                                       \
      for (int j4 = 0; j4 < 4; ++j4)                                          \
        acc[j4] = *(const f32x4*)(b2 + (jh * 4 + j4) * 16 + q * 4);           \
      _Pragma("unroll")                                                       \
      for (int j4 = 0; j4 < 4; ++j4) {                                        \
        int jt = jh * 4 + j4;                                                 \
        _Pragma("unroll")                                                     \
        for (int kt = 0; kt < 4; ++kt) {                                      \
          half8 a = *(const half8*)(wlds + (((jt * 4 + kt) * 64 + lane) << 3)); \
          acc[j4] = __builtin_amdgcn_mfma_f32_16x16x32_f16(a, h1[kt], acc[j4], 0, 0, 0); \
        }                                                                     \
      }                                                                       \
      _Pragma("unroll")                                                       \
      for (int p = 0; p < 2; ++p)                                             \
        h2[jh * 2 + p] = cvt8(relu4(acc[p * 2]), relu4(acc[p * 2 + 1]));      \
    }                                                                         \
    /* ---- layer 3: 4 jt x 4 kt32 -> acc[0..1]=m_, acc[2..3]=a */            \
    _Pragma("unroll")                                                         \
    for (int jt = 0; jt < 4; ++jt)                                            \
      acc[jt] = *(const f32x4*)(b3 + jt * 16 + q * 4);                        \
    _Pragma("unroll")                                                         \
    for (int jt = 0; jt < 4; ++jt) {                                          \
      _Pragma("unroll")                                                       \
      for (int kt = 0; kt < 4; ++kt) {                                        \
        half8 a = *(const half8*)(wlds + (((32 + jt * 4 + kt) * 64 + lane) << 3)); \
        acc[jt] = __builtin_amdgcn_mfma_f32_16x16x32_f16(a, h2[kt], acc[jt], 0, 0, 0); \
      }                                                                       \
    }                                                                         \
    /* ---- epilogue: lane owns row m; x still live in RX */                  \
    {                                                                         \
      long m = blockBase + (IT) * 128 + wid * 16 + c;                         \
      f32x4 xa = RX[0], xb = RX[1];                                           \
      f32x4 ua, ub;                                                           \
      float s = 0.f;                                                          \
      _Pragma("unroll")                                                       \
      for (int i = 0; i < 4; ++i) {                                           \
        float aa = fminf(fmaxf(acc[2][i], -5.f), 5.f);                        \
        float ab = fminf(fmaxf(acc[3][i], -5.f), 5.f);                        \
        ua[i] = (xa[i] - acc[0][i]) * __expf(-aa);                            \
        ub[i] = (xb[i] - acc[1][i]) * __expf(-ab);                            \
        s += aa + ab;                                                         \
      }                                                                       \
      *(f32x4*)(out + m * NI + q * 4) = ua;                                   \
      *(f32x4*)(out + m * NI + 16 + q * 4) = ub;                              \
      s += __shfl_xor(s, 16);                                                 \
      s += __shfl_xor(s, 32);                                                 \
      if (q == 0) out[(long)B_ROWS * NI + m] = -s;                            \
    }                                                                         \
  }

__global__ __launch_bounds__(512, 4) void made_fused(
    const float* __restrict__ x, const float* __restrict__ cond,
    const float* __restrict__ b1, const float* __restrict__ b2,
    const float* __restrict__ b3, const _Float16* __restrict__ wf,
    float* __restrict__ out) {
  // L2+L3 weight fragments staged in LDS: frags 24..71 -> 48 * 1KB = 48KB
  __shared__ __align__(16) _Float16 wlds[48 * 512];

  const int tid  = threadIdx.x;
  const int lane = tid & 63;
  const int wid  = tid >> 6;
  const int q = lane >> 4, c = lane & 15;
  const long blockBase = (long)blockIdx.x * (ITERS * 128);  // 512 rows/block

  // ---- tile-0 activation loads FIRST (oldest vmcnt entries: the body-0
  // cvt can then wait on these WITHOUT draining the newer LDS stage) ----
  f32x4 rxA[2], rcA[4], rxB[2], rcB[4];
  {
    long r = blockBase + wid * 16 + c;
    const f32x4* xr = (const f32x4*)(x + r * NI);
    const f32x4* cr = (const f32x4*)(cond + r * NC);
    rxA[0] = xr[q];     rxA[1] = xr[4 + q];
    rcA[0] = cr[q];     rcA[1] = cr[4 + q];
    rcA[2] = cr[8 + q]; rcA[3] = cr[12 + q];
  }

  // ---- one-time stage: 48KB L2/L3 weights via global_load_lds ----
  {
    const char* gsrc = (const char*)(wf + L2_BASE * 512) + wid * 6144;
    char* ldst = (char*)wlds + wid * 6144;
#pragma unroll
    for (int i = 0; i < 6; ++i) {
      __builtin_amdgcn_global_load_lds(
          (const __attribute__((address_space(1))) void*)(gsrc + i * 1024 + lane * 16),
          (__attribute__((address_space(3))) void*)(ldst + i * 1024),
          16, 0, 0);
    }
  }

  // ---- straight-line stream: 4 bodies, static indices, no back-edge ----
  BODY(rxA, rcA, rxB, rcB, 0, 1);
  BODY(rxB, rcB, rxA, rcA, 1, 0);
  BODY(rxA, rcA, rxB, rcB, 2, 0);
  BODY(rxB, rcB, rxA, rcA, 3, 0);
}

extern "C" void kernel_launch(void* const* d_in, const int* in_sizes, int n_in,
                              void* d_out, int out_size, void* d_ws, size_t ws_size,
                              hipStream_t stream) {
  const float* x    = (const float*)d_in[0];
  const float* cond = (const float*)d_in[1];
  const float* W1   = (const float*)d_in[2];
  const float* b1   = (const float*)d_in[3];
  const float* Wc   = (const float*)d_in[4];
  const float* W2   = (const float*)d_in[5];
  const float* b2   = (const float*)d_in[6];
  const float* W3   = (const float*)d_in[7];
  const float* b3   = (const float*)d_in[8];
  _Float16* wf = (_Float16*)d_ws;  // 72 frags * 512 halfs * 2B = 72 KB

  prep_weights<<<(N_FRAGS * 64 + 255) / 256, 256, 0, stream>>>(W1, Wc, W2, W3, wf);
  made_fused<<<B_ROWS / (ITERS * 128), 512, 0, stream>>>(x, cond, b1, b2, b3, wf, (float*)d_out);
}

// Round 4
// 281.297 us; speedup vs baseline: 3.7027x; 1.1143x over previous
//
#include <hip/hip_runtime.h>

// MADE flow: u = (x - m)*exp(-a), logdet = -sum(a)
// B=524288, NI=32, H=128, NC=64.
// R6: spill elimination. Ideal WRITE=69MB; R0 (bounds(256,3), 170-reg) wrote
// 67.6MB (clean) while R1/R3 (bounds(512,4), 128-reg) wrote 92-96MB -> ~27MB
// scratch spill = dependent global round-trips on every wave's critical path.
// This round: R1's K=32/nt=2 dataflow (best instruction efficiency) at R0's
// spill-free budget: block=256, launch_bounds(256,3) -> 3 blocks/CU (LDS
// 3*48KB=144KB <= 160KB). Register headroom also pays for: x kept live
// through the epilogue (no L2 re-read), act loads issued before the LDS
// stage (oldest vmcnt -> bf cvt doesn't drain the stage).

#define B_ROWS 524288
#define NI 32
#define HD 128
#define NC 64

// K=32 fragments: 1 frag = 16(j) x 32(k) f16 = 512 halfs = 1KB
#define L2_BASE 24    // L1 frags: 8 jt * 3 kt = 24
#define L3_BASE 56    // L2 frags: 8 jt * 4 kt = 32
#define N_FRAGS 72    // L3 frags: 4 jt * 4 kt = 16

typedef _Float16 half8 __attribute__((ext_vector_type(8)));
typedef float f32x4 __attribute__((ext_vector_type(4)));

__device__ inline f32x4 relu4(f32x4 v) {
  v[0] = fmaxf(v[0], 0.f); v[1] = fmaxf(v[1], 0.f);
  v[2] = fmaxf(v[2], 0.f); v[3] = fmaxf(v[3], 0.f);
  return v;
}

__device__ inline half8 cvt8(f32x4 lo, f32x4 hi) {
  half8 h;
  h[0] = (_Float16)lo[0]; h[1] = (_Float16)lo[1];
  h[2] = (_Float16)lo[2]; h[3] = (_Float16)lo[3];
  h[4] = (_Float16)hi[0]; h[5] = (_Float16)hi[1];
  h[6] = (_Float16)hi[2]; h[7] = (_Float16)hi[3];
  return h;
}

// ---------------- prep: masked f16 weights in K=32 MFMA-A fragment order ----
// Fragment (frag, lane) holds A[m][k]: m = jt*16 + (lane&15),
// k = kt*32 + (e>>2)*16 + (lane>>4)*4 + (e&3)  (e=0..7, two stacked K=16
// halves). Stored at wf[frag*512 + lane*8 + e].
__global__ void prep_weights(const float* __restrict__ W1, const float* __restrict__ Wc,
                             const float* __restrict__ W2, const float* __restrict__ W3,
                             _Float16* __restrict__ wf) {
  int tid = blockIdx.x * blockDim.x + threadIdx.x;
  if (tid >= N_FRAGS * 64) return;
  int frag = tid >> 6;
  int lane = tid & 63;
  int q = lane >> 4, c = lane & 15;
  int L, jt, kt;
  if (frag < L2_BASE)      { L = 0; jt = frag / 3;              kt = frag % 3; }
  else if (frag < L3_BASE) { L = 1; jt = (frag - L2_BASE) >> 2; kt = (frag - L2_BASE) & 3; }
  else                     { L = 2; jt = (frag - L3_BASE) >> 2; kt = (frag - L3_BASE) & 3; }
  int j = jt * 16 + c;  // output unit (row of W)
  half8 v;
#pragma unroll
  for (int e = 0; e < 8; ++e) {
    int k = kt * 32 + (e >> 2) * 16 + q * 4 + (e & 3);
    float w;
    if (L == 0) {
      // layer1 K-dim is [x(32) | cond(64)]; mask m1 = (j%31 >= k), Wc unmasked
      if (k < NI) w = ((j % 31) >= k) ? W1[j * NI + k] : 0.f;
      else        w = Wc[j * NC + (k - NI)];
    } else if (L == 1) {
      w = ((j % 31) >= (k % 31)) ? W2[j * HD + k] : 0.f;          // m2
    } else {
      w = (((j % 32) - 1) >= (k % 31)) ? W3[j * HD + k] : 0.f;    // m3
    }
    v[e] = (_Float16)w;
  }
  *(half8*)(wf + (size_t)tid * 8) = v;
}

// ---------------- fused main kernel ----------------
// 4 waves/block, each wave owns 32 batch rows (nt = 2 tiles of 16).
// Grid = B/(4*32) = 4096 blocks. launch_bounds(256,3): 170-reg budget,
// no spill; 3 blocks/CU (12 waves) by both regs and LDS.
__global__ __launch_bounds__(256, 3) void made_fused(
    const float* __restrict__ x, const float* __restrict__ cond,
    const float* __restrict__ b1, const float* __restrict__ b2,
    const float* __restrict__ b3, const _Float16* __restrict__ wf,
    float* __restrict__ out) {
  // L2+L3 weight fragments staged in LDS: frags 24..71 -> 48 * 1KB = 48KB
  __shared__ __align__(16) _Float16 wlds[48 * 512];

  const int tid  = threadIdx.x;
  const int lane = tid & 63;
  const int wid  = tid >> 6;
  const int q = lane >> 4, c = lane & 15;
  const long rowbase = ((long)blockIdx.x * 4 + wid) * 32;

  // ---- activation loads FIRST (oldest vmcnt entries: the bf cvt waits on
  // these without draining the newer 48KB LDS stage). x kept LIVE to the
  // epilogue (no re-read at the end of the wave's chain).
  f32x4 xv[2][2], cv[2][4];
#pragma unroll
  for (int nt = 0; nt < 2; ++nt) {
    const f32x4* xr = (const f32x4*)(x    + (rowbase + nt * 16 + c) * NI);
    const f32x4* cr = (const f32x4*)(cond + (rowbase + nt * 16 + c) * NC);
    xv[nt][0] = xr[q];     xv[nt][1] = xr[4 + q];
    cv[nt][0] = cr[q];     cv[nt][1] = cr[4 + q];
    cv[nt][2] = cr[8 + q]; cv[nt][3] = cr[12 + q];
  }

  // ---- one-time stage: 48KB L2/L3 weights via global_load_lds (12KB/wave) --
  {
    const char* gsrc = (const char*)(wf + L2_BASE * 512) + wid * 12288;
    char* ldst = (char*)wlds + wid * 12288;
#pragma unroll
    for (int i = 0; i < 12; ++i) {
      __builtin_amdgcn_global_load_lds(
          (const __attribute__((address_space(1))) void*)(gsrc + i * 1024 + lane * 16),
          (__attribute__((address_space(3))) void*)(ldst + i * 1024),
          16, 0, 0);
    }
  }

  // ---- B-fragments for layer 1 (K=96 over [x|cond])
  half8 bf[3][2];
#pragma unroll
  for (int nt = 0; nt < 2; ++nt) {
    bf[0][nt] = cvt8(xv[nt][0], xv[nt][1]);
    bf[1][nt] = cvt8(cv[nt][0], cv[nt][1]);
    bf[2][nt] = cvt8(cv[nt][2], cv[nt][3]);
  }

  // ---- layer 1: 8 jt x 3 kt32, weights from GLOBAL (L2-resident; overlaps
  // the LDS stage). jh-split keeps the live acc file at 32 regs.
  f32x4 acc[4][2];
  half8 h1[4][2];
#pragma unroll
  for (int jh = 0; jh < 2; ++jh) {
#pragma unroll
    for (int j4 = 0; j4 < 4; ++j4) {
      f32x4 bv = *(const f32x4*)(b1 + (jh * 4 + j4) * 16 + q * 4);
      acc[j4][0] = bv; acc[j4][1] = bv;
    }
#pragma unroll
    for (int j4 = 0; j4 < 4; ++j4) {
      int jt = jh * 4 + j4;
#pragma unroll
      for (int kt = 0; kt < 3; ++kt) {
        half8 a = *(const half8*)(wf + (((jt * 3 + kt) * 64 + lane) << 3));
#pragma unroll
        for (int nt = 0; nt < 2; ++nt)
          acc[j4][nt] = __builtin_amdgcn_mfma_f32_16x16x32_f16(a, bf[kt][nt], acc[j4][nt], 0, 0, 0);
      }
    }
    // C/D tile pair (2p, 2p+1) == lower/upper K=16 halves of next-layer B frag
#pragma unroll
    for (int p = 0; p < 2; ++p)
#pragma unroll
      for (int nt = 0; nt < 2; ++nt)
        h1[jh * 2 + p][nt] = cvt8(relu4(acc[p * 2][nt]), relu4(acc[p * 2 + 1][nt]));
  }

  __syncthreads();  // LDS weights ready; all later weight reads hit LDS

  // ---- layer 2: 8 jt x 4 kt32, weights from LDS
  half8 h2[4][2];
#pragma unroll
  for (int jh = 0; jh < 2; ++jh) {
#pragma unroll
    for (int j4 = 0; j4 < 4; ++j4) {
      f32x4 bv = *(const f32x4*)(b2 + (jh * 4 + j4) * 16 + q * 4);
      acc[j4][0] = bv; acc[j4][1] = bv;
    }
#pragma unroll
    for (int j4 = 0; j4 < 4; ++j4) {
      int jt = jh * 4 + j4;
#pragma unroll
      for (int kt = 0; kt < 4; ++kt) {
        half8 a = *(const half8*)(wlds + (((jt * 4 + kt) * 64 + lane) << 3));
#pragma unroll
        for (int nt = 0; nt < 2; ++nt)
          acc[j4][nt] = __builtin_amdgcn_mfma_f32_16x16x32_f16(a, h1[kt][nt], acc[j4][nt], 0, 0, 0);
      }
    }
#pragma unroll
    for (int p = 0; p < 2; ++p)
#pragma unroll
      for (int nt = 0; nt < 2; ++nt)
        h2[jh * 2 + p][nt] = cvt8(relu4(acc[p * 2][nt]), relu4(acc[p * 2 + 1][nt]));
  }

  // ---- layer 3: 4 jt x 4 kt32, weights from LDS; acc[0..1]=m_, acc[2..3]=a
#pragma unroll
  for (int jt = 0; jt < 4; ++jt) {
    f32x4 bv = *(const f32x4*)(b3 + jt * 16 + q * 4);
    acc[jt][0] = bv; acc[jt][1] = bv;
  }
#pragma unroll
  for (int jt = 0; jt < 4; ++jt)
#pragma unroll
    for (int kt = 0; kt < 4; ++kt) {
      half8 a = *(const half8*)(wlds + (((32 + jt * 4 + kt) * 64 + lane) << 3));
#pragma unroll
      for (int nt = 0; nt < 2; ++nt)
        acc[jt][nt] = __builtin_amdgcn_mfma_f32_16x16x32_f16(a, h2[kt][nt], acc[jt][nt], 0, 0, 0);
    }

  // ---- epilogue: lane owns batch row m = rowbase+nt*16+c; x is still live.
#pragma unroll
  for (int nt = 0; nt < 2; ++nt) {
    long m = rowbase + nt * 16 + c;
    f32x4 xa = xv[nt][0], xb = xv[nt][1];
    f32x4 mva = acc[0][nt], mvb = acc[1][nt];
    f32x4 ava = acc[2][nt], avb = acc[3][nt];
    f32x4 ua, ub;
    float s = 0.f;
#pragma unroll
    for (int i = 0; i < 4; ++i) {
      float aa = fminf(fmaxf(ava[i], -5.f), 5.f);
      float ab = fminf(fmaxf(avb[i], -5.f), 5.f);
      ua[i] = (xa[i] - mva[i]) * __expf(-aa);
      ub[i] = (xb[i] - mvb[i]) * __expf(-ab);
      s += aa + ab;
    }
    *(f32x4*)(out + m * NI + q * 4) = ua;
    *(f32x4*)(out + m * NI + 16 + q * 4) = ub;
    s += __shfl_xor(s, 16);
    s += __shfl_xor(s, 32);
    if (q == 0) out[(long)B_ROWS * NI + m] = -s;  // logdet
  }
}

extern "C" void kernel_launch(void* const* d_in, const int* in_sizes, int n_in,
                              void* d_out, int out_size, void* d_ws, size_t ws_size,
                              hipStream_t stream) {
  const float* x    = (const float*)d_in[0];
  const float* cond = (const float*)d_in[1];
  const float* W1   = (const float*)d_in[2];
  const float* b1   = (const float*)d_in[3];
  const float* Wc   = (const float*)d_in[4];
  const float* W2   = (const float*)d_in[5];
  const float* b2   = (const float*)d_in[6];
  const float* W3   = (const float*)d_in[7];
  const float* b3   = (const float*)d_in[8];
  _Float16* wf = (_Float16*)d_ws;  // 72 frags * 512 halfs * 2B = 72 KB

  prep_weights<<<(N_FRAGS * 64 + 255) / 256, 256, 0, stream>>>(W1, Wc, W2, W3, wf);
  made_fused<<<B_ROWS / 128, 256, 0, stream>>>(x, cond, b1, b2, b3, wf, (float*)d_out);
}